// Round 10
// baseline (166.806 us; speedup 1.0000x reference)
//
#include <hip/hip_runtime.h>

// AntModel: counts flow through 3 routing layers.
//   dest_k[s] = argmax_j W_k[s, j]   (first max index, ties broken low)
//   out[b, dest3[dest2[dest1[s]]]] += x[b, s]; relu is identity on counts.
//
// Round-10: PRUNED argmax chain. Only rows of W2 in the image of dest1
//   (~63%) and rows of W3 in the image of dest2∘dest1 (~47%) are ever
//   consulted — skip the rest. Demand drops 144 -> ~112MB at the measured
//   (structure-invariant, rounds 1/2/4/7) ~3.8 TB/s nt-read service rate.
//   Chain: K1 argmax(W1)+zero flags -> K2 mark used2 -> K3 argmax(W2|used2)
//   -> K4 mark used3 -> K5 argmax(W3|used3) -> K6 scatter(+compose in LDS).
//   Dispatch boundaries are ~free under graph capture (round 9: 3->2 null).
//   All loads NON-TEMPORAL: the harness's 2^28-byte poison fill churns the
//   entire L3 each iteration; nt bypass avoids the mixed hit/miss regime
//   (round 6: 56 -> <40us). No cooperative launch (round 8: fails capture).

#define N_IN   4096
#define N_MID  4096
#define N_OUT  1024
#define BATCH  256

typedef float f4 __attribute__((ext_vector_type(4)));

__device__ __forceinline__ void upd(float v, int idx, float& bv, int& bi) {
    // strictly-greater keeps the FIRST occurrence of the max (jnp.argmax semantics)
    if (v > bv || (v == bv && idx < bi)) { bv = v; bi = idx; }
}

template <int NCOLS>
__device__ __forceinline__ void row_argmax(const float* __restrict__ W, int row,
                                           int* __restrict__ dest) {
    const int lane = threadIdx.x & 63;
    const f4* __restrict__ p =
        reinterpret_cast<const f4*>(W + (size_t)row * NCOLS);
    float bv = -__builtin_huge_valf();
    int bi = 0;
    constexpr int ITERS = NCOLS / 256;              // 16 (4096 cols) or 4 (1024)
    constexpr int BAT   = (ITERS >= 8) ? 8 : ITERS; // loads kept in flight
    #pragma unroll
    for (int t0 = 0; t0 < ITERS; t0 += BAT) {
        f4 v[BAT];
        #pragma unroll
        for (int u = 0; u < BAT; ++u)
            v[u] = __builtin_nontemporal_load(p + (size_t)(t0 + u) * 64 + lane);
        __builtin_amdgcn_sched_barrier(0);  // pin the load batch above the consume
        #pragma unroll
        for (int u = 0; u < BAT; ++u) {
            int c = (t0 + u) * 256 + lane * 4;
            upd(v[u].x, c + 0, bv, bi);
            upd(v[u].y, c + 1, bv, bi);
            upd(v[u].z, c + 2, bv, bi);
            upd(v[u].w, c + 3, bv, bi);
        }
    }
    // wave-64 butterfly reduce; (value desc, index asc) is a total order so
    // xor-reduce is associative/commutative-safe.
    #pragma unroll
    for (int off = 1; off < 64; off <<= 1) {
        float ov = __shfl_xor(bv, off, 64);
        int   oi = __shfl_xor(bi, off, 64);
        if (ov > bv || (ov == bv && oi < bi)) { bv = ov; bi = oi; }
    }
    if (lane == 0) dest[row] = bi;
}

// K1: full argmax of W1 (4096 waves = grid exactly); first 8192 threads also
// zero the used2/used3 flags (read only after the next dispatch boundary).
__global__ __launch_bounds__(256) void argmax_w1_kernel(
    const float* __restrict__ W1, int* __restrict__ dest1,
    int* __restrict__ used2, int* __restrict__ used3) {
    const int g = blockIdx.x * 256 + threadIdx.x;
    if (g < N_MID) used2[g] = 0;
    else if (g < 2 * N_MID) used3[g - N_MID] = 0;
    row_argmax<N_MID>(W1, g >> 6, dest1);
}

// K2: mark rows of W2 actually consulted. Racy same-value stores are benign.
__global__ __launch_bounds__(256) void mark2_kernel(
    const int* __restrict__ dest1, int* __restrict__ used2) {
    const int g = blockIdx.x * 256 + threadIdx.x;   // 4096 threads
    used2[dest1[g]] = 1;
}

// K4: mark rows of W3 consulted (dest2 defined wherever used2 was set).
__global__ __launch_bounds__(256) void mark3_kernel(
    const int* __restrict__ dest1, const int* __restrict__ dest2,
    int* __restrict__ used3) {
    const int g = blockIdx.x * 256 + threadIdx.x;   // 4096 threads
    used3[dest2[dest1[g]]] = 1;
}

// K3/K5: argmax only where the row is marked; unused dest entries stay
// garbage and are never read downstream.
template <int NCOLS>
__global__ __launch_bounds__(256) void argmax_pruned_kernel(
    const float* __restrict__ W, const int* __restrict__ used,
    int* __restrict__ dest) {
    const int wave = (blockIdx.x * 256 + threadIdx.x) >> 6;
    if (!used[wave]) return;
    row_argmax<NCOLS>(W, wave, dest);
}

// K6: per-batch scatter with the routing composition recomputed into LDS
// (L2-hot 16KB tables; removes the compose kernel + global fdest).
__global__ __launch_bounds__(1024) void scatter_fused_kernel(
    const int* __restrict__ x, const int* __restrict__ dest1,
    const int* __restrict__ dest2, const int* __restrict__ dest3,
    float* __restrict__ out) {
    __shared__ int fd[N_IN];     // 16KB
    __shared__ int cnt[N_OUT];   // 4KB
    const int b   = blockIdx.x;
    const int tid = threadIdx.x;

    cnt[tid] = 0;   // 1024 threads cover N_OUT exactly
    #pragma unroll
    for (int k = 0; k < N_IN / 1024; ++k) {
        int s = tid + k * 1024;
        fd[s] = dest3[dest2[dest1[s]]];
    }
    __syncthreads();

    const int4 v = reinterpret_cast<const int4*>(x + (size_t)b * N_IN)[tid];
    const int4 d = *reinterpret_cast<const int4*>(&fd[tid * 4]);
    atomicAdd(&cnt[d.x], v.x);
    atomicAdd(&cnt[d.y], v.y);
    atomicAdd(&cnt[d.z], v.z);
    atomicAdd(&cnt[d.w], v.w);
    __syncthreads();
    out[(size_t)b * N_OUT + tid] = (float)cnt[tid];
}

extern "C" void kernel_launch(void* const* d_in, const int* in_sizes, int n_in,
                              void* d_out, int out_size, void* d_ws, size_t ws_size,
                              hipStream_t stream) {
    const int*   x  = (const int*)d_in[0];
    const float* W1 = (const float*)d_in[1];
    const float* W2 = (const float*)d_in[2];
    const float* W3 = (const float*)d_in[3];
    float* out = (float*)d_out;

    int* ws    = (int*)d_ws;
    int* dest1 = ws;               // [4096]
    int* dest2 = ws + N_IN;        // [4096]
    int* dest3 = ws + 2 * N_IN;    // [4096] rows of W3
    int* used2 = ws + 3 * N_IN;    // [4096] flags
    int* used3 = ws + 4 * N_IN;    // [4096] flags

    argmax_w1_kernel<<<N_IN / 4, 256, 0, stream>>>(W1, dest1, used2, used3);
    mark2_kernel<<<N_IN / 256, 256, 0, stream>>>(dest1, used2);
    argmax_pruned_kernel<N_MID><<<N_MID / 4, 256, 0, stream>>>(W2, used2, dest2);
    mark3_kernel<<<N_IN / 256, 256, 0, stream>>>(dest1, dest2, used3);
    argmax_pruned_kernel<N_OUT><<<N_MID / 4, 256, 0, stream>>>(W3, used3, dest3);
    scatter_fused_kernel<<<BATCH, 1024, 0, stream>>>(x, dest1, dest2, dest3, out);
}

// Round 12
// 158.234 us; speedup vs baseline: 1.0542x; 1.0542x over previous
//
#include <hip/hip_runtime.h>

// AntModel: counts flow through 3 routing layers.
//   dest_k[s] = argmax_j W_k[s, j]   (first max index, ties broken low)
//   out[b, dest3[dest2[dest1[s]]]] += x[b, s]; relu is identity on counts.
//
// FINAL (round-9 structure, session best 158.6us; round-11 was an infra
// failure — this is a byte-identical resubmit of the verified kernel).
//   Kernel 1: wave-per-row argmax with 8-deep NON-TEMPORAL load batches.
//     nt bypasses L3 allocation — the harness's 2^28-byte poison fill churns
//     the entire 256MiB L3 every iteration, so plain loads hit a mixed
//     L3-hit/HBM-miss regime (56us); nt streams pure-HBM (~40us, -13us win,
//     round 6). The nt read service rate (~3.7 TB/s) is structure-invariant:
//     MLP depth 1/6/16 (rounds 1-2), block-burst dispersion (rounds 4,7),
//     image-pruned demand (round 10, regressed: serialization tax > byte
//     savings) all null or worse.
//   Kernel 2: scatter with compose fused — each block recomputes the 4096-
//     entry routing composition into LDS from the three L2-hot 16KB tables
//     (round 9: null vs separate compose kernel, kept for fewer dispatches).
//   Cooperative full fusion impossible: hipLaunchCooperativeKernel fails
//   under the harness's graph capture (round 8: zero output).

#define N_IN   4096
#define N_MID  4096
#define N_OUT  1024
#define BATCH  256

typedef float f4 __attribute__((ext_vector_type(4)));

__device__ __forceinline__ void upd(float v, int idx, float& bv, int& bi) {
    // strictly-greater keeps the FIRST occurrence of the max (jnp.argmax semantics)
    if (v > bv || (v == bv && idx < bi)) { bv = v; bi = idx; }
}

template <int NCOLS>
__device__ __forceinline__ void row_argmax(const float* __restrict__ W, int row,
                                           int* __restrict__ dest) {
    const int lane = threadIdx.x & 63;
    const f4* __restrict__ p =
        reinterpret_cast<const f4*>(W + (size_t)row * NCOLS);
    float bv = -__builtin_huge_valf();
    int bi = 0;
    constexpr int ITERS = NCOLS / 256;              // 16 (4096 cols) or 4 (1024)
    constexpr int BAT   = (ITERS >= 8) ? 8 : ITERS; // loads kept in flight
    #pragma unroll
    for (int t0 = 0; t0 < ITERS; t0 += BAT) {
        f4 v[BAT];
        #pragma unroll
        for (int u = 0; u < BAT; ++u)
            v[u] = __builtin_nontemporal_load(p + (size_t)(t0 + u) * 64 + lane);
        __builtin_amdgcn_sched_barrier(0);  // pin the load batch above the consume
        #pragma unroll
        for (int u = 0; u < BAT; ++u) {
            int c = (t0 + u) * 256 + lane * 4;
            upd(v[u].x, c + 0, bv, bi);
            upd(v[u].y, c + 1, bv, bi);
            upd(v[u].z, c + 2, bv, bi);
            upd(v[u].w, c + 3, bv, bi);
        }
    }
    // wave-64 butterfly reduce; (value desc, index asc) is a total order so
    // xor-reduce is associative/commutative-safe.
    #pragma unroll
    for (int off = 1; off < 64; off <<= 1) {
        float ov = __shfl_xor(bv, off, 64);
        int   oi = __shfl_xor(bi, off, 64);
        if (ov > bv || (ov == bv && oi < bi)) { bv = ov; bi = oi; }
    }
    if (lane == 0) dest[row] = bi;
}

__global__ __launch_bounds__(256) void argmax_all_kernel(
    const float* __restrict__ W1, const float* __restrict__ W2,
    const float* __restrict__ W3, int* __restrict__ dest1,
    int* __restrict__ dest2, int* __restrict__ dest3) {
    const int wave = (blockIdx.x * blockDim.x + threadIdx.x) >> 6;
    if (wave < N_IN) {
        row_argmax<N_MID>(W1, wave, dest1);
    } else if (wave < N_IN + N_MID) {
        row_argmax<N_MID>(W2, wave - N_IN, dest2);
    } else {
        row_argmax<N_OUT>(W3, wave - (N_IN + N_MID), dest3);
    }
}

__global__ __launch_bounds__(1024) void scatter_fused_kernel(
    const int* __restrict__ x, const int* __restrict__ dest1,
    const int* __restrict__ dest2, const int* __restrict__ dest3,
    float* __restrict__ out) {
    __shared__ int fd[N_IN];     // 16KB: composed routing, block-private
    __shared__ int cnt[N_OUT];   // 4KB
    const int b   = blockIdx.x;
    const int tid = threadIdx.x;

    cnt[tid] = 0;   // 1024 threads cover N_OUT exactly
    // Compose: 4 sources/thread, stride-1024 so dest1 reads coalesce; the
    // chained dest2/dest3 gathers hit the L2-hot 16KB tables.
    #pragma unroll
    for (int k = 0; k < N_IN / 1024; ++k) {
        int s = tid + k * 1024;
        fd[s] = dest3[dest2[dest1[s]]];
    }
    __syncthreads();

    // 4096 sources / 1024 threads: one int4 of counts, one LDS int4 of dests.
    const int4 v = reinterpret_cast<const int4*>(x + (size_t)b * N_IN)[tid];
    const int4 d = *reinterpret_cast<const int4*>(&fd[tid * 4]);
    atomicAdd(&cnt[d.x], v.x);
    atomicAdd(&cnt[d.y], v.y);
    atomicAdd(&cnt[d.z], v.z);
    atomicAdd(&cnt[d.w], v.w);
    __syncthreads();
    out[(size_t)b * N_OUT + tid] = (float)cnt[tid];
}

extern "C" void kernel_launch(void* const* d_in, const int* in_sizes, int n_in,
                              void* d_out, int out_size, void* d_ws, size_t ws_size,
                              hipStream_t stream) {
    const int*   x  = (const int*)d_in[0];
    const float* W1 = (const float*)d_in[1];
    const float* W2 = (const float*)d_in[2];
    const float* W3 = (const float*)d_in[3];
    float* out = (float*)d_out;

    int* ws    = (int*)d_ws;
    int* dest1 = ws;               // [4096]
    int* dest2 = ws + N_IN;        // [4096]
    int* dest3 = ws + 2 * N_IN;    // [4096] rows of W3

    // 12288 rows total, 1 wave each, 4 waves per 256-thread block.
    const int total_waves = N_IN + N_MID + N_MID;  // 4096*3
    argmax_all_kernel<<<total_waves / 4, 256, 0, stream>>>(W1, W2, W3,
                                                           dest1, dest2, dest3);
    scatter_fused_kernel<<<BATCH, 1024, 0, stream>>>(x, dest1, dest2, dest3, out);
}